// Round 9
// baseline (731.531 us; speedup 1.0000x reference)
//
#include <hip/hip_runtime.h>

#define NN 100000
#define NE 1600000
#define LAM 0.05f

typedef __attribute__((ext_vector_type(8))) short bf16x8;
typedef __attribute__((ext_vector_type(8))) unsigned short u16x8;
typedef __attribute__((ext_vector_type(4))) float f32x4;
typedef unsigned short ushort_t;

__device__ inline unsigned short f2bf(float x) {
  unsigned u = __builtin_bit_cast(unsigned, x);
  u = (u + 0x7FFFu + ((u >> 16) & 1u)) >> 16;
  return (unsigned short)u;
}
__device__ inline float bf2f(unsigned short h) {
  unsigned u = ((unsigned)h) << 16;
  return __builtin_bit_cast(float, u);
}
__device__ inline u16x8 pack2(float4 a, float4 b) {
  u16x8 p;
  p[0]=f2bf(a.x); p[1]=f2bf(a.y); p[2]=f2bf(a.z); p[3]=f2bf(a.w);
  p[4]=f2bf(b.x); p[5]=f2bf(b.y); p[6]=f2bf(b.z); p[7]=f2bf(b.w);
  return p;
}
__device__ inline u16x8 zero8() {
  u16x8 z;
  #pragma unroll
  for (int i = 0; i < 8; ++i) z[i] = 0;
  return z;
}
__device__ inline f32x4 zero4() {
  f32x4 z;
  z[0] = z[1] = z[2] = z[3] = 0.f;
  return z;
}

#define MFMA(a,b,c) __builtin_amdgcn_mfma_f32_16x16x32_bf16((bf16x8)(a),(bf16x8)(b),(c),0,0,0)

// ============ Kernel 1: V|T = H @ [Wv|Wt]^T via MFMA, bf16 output ============
#define K1S 136
__global__ __launch_bounds__(256) void k1_vt(
    const float* __restrict__ H, const float* __restrict__ Wv,
    const float* __restrict__ Wt, ushort_t* __restrict__ V, ushort_t* __restrict__ T)
{
  __shared__ unsigned short Wl[128*K1S];
  __shared__ unsigned short Hs[64*K1S];
  const int tid = threadIdx.x;
  for (int idx = tid; idx < 128*16; idx += 256) {
    int c = idx >> 4, k = (idx & 15) * 8;
    const float* src = (c < 64) ? (Wv + c*128 + k) : (Wt + (c-64)*128 + k);
    *(u16x8*)&Wl[c*K1S + k] = pack2(*(const float4*)src, *(const float4*)(src+4));
  }
  __syncthreads();
  const int wv = tid >> 6, l = tid & 63, l15 = l & 15, lh = l >> 4;
  const int ntiles = (NN + 63) >> 6;
  for (int t = blockIdx.x; t < ntiles; t += gridDim.x) {
    const int nb = t * 64;
    {
      const int r = tid >> 2, q = tid & 3, row = nb + r;
      if (row < NN) {
        const float* src = H + row*128 + q*32;
        #pragma unroll
        for (int s = 0; s < 4; ++s)
          *(u16x8*)&Hs[r*K1S + q*32 + s*8] =
              pack2(*(const float4*)(src + s*8), *(const float4*)(src + s*8 + 4));
      } else {
        #pragma unroll
        for (int s = 0; s < 4; ++s) *(u16x8*)&Hs[r*K1S + q*32 + s*8] = zero8();
      }
    }
    __syncthreads();
    f32x4 acc[4][2];
    #pragma unroll
    for (int m = 0; m < 4; ++m) { acc[m][0] = zero4(); acc[m][1] = zero4(); }
    #pragma unroll
    for (int kk = 0; kk < 128; kk += 32) {
      const int kb = kk + lh*8;
      bf16x8 bf0 = *(const bf16x8*)&Wl[(wv*32 + l15)*K1S + kb];
      bf16x8 bf1 = *(const bf16x8*)&Wl[(wv*32 + 16 + l15)*K1S + kb];
      #pragma unroll
      for (int m = 0; m < 4; ++m) {
        bf16x8 af = *(const bf16x8*)&Hs[(m*16 + l15)*K1S + kb];
        acc[m][0] = MFMA(af, bf0, acc[m][0]);
        acc[m][1] = MFMA(af, bf1, acc[m][1]);
      }
    }
    #pragma unroll
    for (int m = 0; m < 4; ++m) {
      const int rowl = m*16 + lh*4;
      #pragma unroll
      for (int n = 0; n < 2; ++n) {
        const int col = wv*32 + n*16 + l15;
        #pragma unroll
        for (int r = 0; r < 4; ++r) {
          const int node = nb + rowl + r;
          if (node < NN) {
            if (col < 64) V[node*64 + col] = f2bf(acc[m][n][r]);
            else          T[node*64 + col - 64] = f2bf(acc[m][n][r]);
          }
        }
      }
    }
    __syncthreads();
  }
}

// ============ k_fill: bucket signed edges by destination col ============
// elist[col*64 + slot] = edge id, bit30 set for negative sign. ~1.07M int atomics.
__global__ __launch_bounds__(256) void k_fill(
    const int* __restrict__ eidx, const int* __restrict__ esign,
    int* __restrict__ cursor, int* __restrict__ elist)
{
  int e = blockIdx.x*256 + threadIdx.x;
  const int stride = gridDim.x*256;
  for (; e < NE; e += stride) {
    const int sg = esign[e];
    if (sg == 0) continue;
    const int col = eidx[NE + e];
    const int slot = atomicAdd(&cursor[col], 1);
    if (slot < 64) elist[col*64 + slot] = (sg > 0) ? e : (e | 0x40000000);
  }
}

// ============ k2_alpha: edge MLP -> softshrunk alpha (no scatter) ============
#define WS 168
__global__ __launch_bounds__(512, 4) void k2_alpha(
    const ushort_t* __restrict__ V, const ushort_t* __restrict__ T,
    const float* __restrict__ semb, const float* __restrict__ w1,
    const float* __restrict__ b1, const float* __restrict__ w2,
    const float* __restrict__ b2, const int* __restrict__ eidx,
    const int* __restrict__ esign, float* __restrict__ w_e,
    float* __restrict__ loss)
{
  __shared__ unsigned short Wl[128*WS];      // w1 bf16 [hid][k], k 136..159 zero
  const int tid = threadIdx.x;
  for (int idx = tid; idx < 128*17; idx += 512) {
    int c = idx / 17, kc = (idx % 17) * 8;
    const float* src = w1 + c*136 + kc;
    *(u16x8*)&Wl[c*WS + kc] = pack2(*(const float4*)src, *(const float4*)(src+4));
  }
  for (int idx = tid; idx < 128*3; idx += 512) {
    int c = idx / 3, s = idx % 3;
    *(u16x8*)&Wl[c*WS + 136 + s*8] = zero8();
  }
  __syncthreads();

  const int wv = tid >> 6, l = tid & 63, l15 = l & 15, lh = l >> 4;
  float b1v[8], w2v[8];
  #pragma unroll
  for (int n = 0; n < 8; ++n) { b1v[n] = b1[n*16 + l15]; w2v[n] = w2[n*16 + l15]; }
  const float b2v = b2[0];
  float loss_acc = 0.f;

  const int wg = blockIdx.x*8 + wv, nw = gridDim.x*8;
  const int NT = NE / 16;

  int t = wg;
  int rj = 0, ci = 0, sg = 0;
  if (t < NT) {                              // per-lane: edge e = t*16 + l15
    const int e = t*16 + l15;
    rj = eidx[e]; ci = eidx[NE + e]; sg = esign[e];
  }
  for (; t < NT; t += nw) {
    // ---- A-fragments straight from global bf16 V/T ----
    bf16x8 A0 = *(const bf16x8*)&T[ci*64 + lh*8];
    bf16x8 A1 = *(const bf16x8*)&T[ci*64 + 32 + lh*8];
    bf16x8 A2 = *(const bf16x8*)&V[rj*64 + lh*8];
    bf16x8 A3 = *(const bf16x8*)&V[rj*64 + 32 + lh*8];
    bf16x8 A4;
    if (lh == 0) {
      const float* sp = semb + (sg + 1) * 8;
      A4 = (bf16x8)pack2(*(const float4*)sp, *(const float4*)(sp+4));
    } else A4 = (bf16x8)zero8();
    // ---- prefetch next tile's indices ----
    int rjn = 0, cin = 0, sgp = 0;
    const int tn = t + nw;
    if (tn < NT) {
      const int en = tn*16 + l15;
      rjn = eidx[en]; cin = eidx[NE + en]; sgp = esign[en];
    }
    // ---- MFMA: rows = 16 edges, cols = 128 hid, K = 160 ----
    f32x4 acc[8];
    #pragma unroll
    for (int n = 0; n < 8; ++n) acc[n] = zero4();
    __builtin_amdgcn_s_setprio(1);
    #pragma unroll
    for (int n = 0; n < 8; ++n) {
      const int rowb = (n*16 + l15)*WS;
      acc[n] = MFMA(A0, *(const bf16x8*)&Wl[rowb + lh*8],       acc[n]);
      acc[n] = MFMA(A1, *(const bf16x8*)&Wl[rowb + 32 + lh*8],  acc[n]);
      acc[n] = MFMA(A2, *(const bf16x8*)&Wl[rowb + 64 + lh*8],  acc[n]);
      acc[n] = MFMA(A3, *(const bf16x8*)&Wl[rowb + 96 + lh*8],  acc[n]);
      acc[n] = MFMA(A4, *(const bf16x8*)&Wl[rowb + 128 + lh*8], acc[n]);
    }
    __builtin_amdgcn_s_setprio(0);
    // ---- relu + w2 dot (in-lane over n), reduce over l15 ----
    f32x4 s;
    #pragma unroll
    for (int r = 0; r < 4; ++r) {
      float a = 0.f;
      #pragma unroll
      for (int n = 0; n < 8; ++n) {
        float hh = acc[n][r] + b1v[n];
        hh = fmaxf(hh, 0.f);
        a = fmaf(hh, w2v[n], a);
      }
      s[r] = a;
    }
    #pragma unroll
    for (int off = 1; off < 16; off <<= 1) {
      #pragma unroll
      for (int r = 0; r < 4; ++r) s[r] += __shfl_xor(s[r], off, 16);
    }
    f32x4 sa;                                   // alpha for edge lh*4+r
    #pragma unroll
    for (int r = 0; r < 4; ++r) {
      float a = s[r] + b2v;
      sa[r] = (a > LAM) ? (a - LAM) : ((a < -LAM) ? (a + LAM) : 0.f);
    }
    if (l15 == 0) {
      #pragma unroll
      for (int r = 0; r < 4; ++r) loss_acc += fabsf(sa[r]);
      *(f32x4*)&w_e[t*16 + lh*4] = sa;          // coalesced 16B per writer lane
    }
    rj = rjn; ci = cin; sg = sgp;
  }
  #pragma unroll
  for (int off = 1; off < 64; off <<= 1) loss_acc += __shfl_xor(loss_acc, off, 64);
  if (l == 0) atomicAdd(loss, loss_acc);
}

// ============ k2b_gather: per-node gather-reduce (no atomics) ============
__global__ __launch_bounds__(256) void k2b_gather(
    const int* __restrict__ cursor, const int* __restrict__ elist,
    const float* __restrict__ w_e, const int* __restrict__ eidx,
    const ushort_t* __restrict__ V, ushort_t* __restrict__ agg)
{
  const int node = blockIdx.x*4 + (threadIdx.x >> 6);
  const int l = threadIdx.x & 63;
  if (node >= NN) return;
  const int dc = cursor[node];
  const int deg = dc < 64 ? dc : 64;
  float acc = 0.f;
  int r_l = 0; float w_l = 0.f;
  if (l < deg) {                      // preload this node's edges (coalesced row)
    const int entry = elist[node*64 + l];
    const int e = entry & 0x3FFFFFFF;
    const float s = w_e[e];
    w_l = (entry & 0x40000000) ? -fabsf(s) : s;
    r_l = eidx[e];
  }
  for (int i = 0; i < deg; ++i) {
    const int   r = __shfl(r_l, i, 64);       // wave-uniform readlane
    const float w = __shfl(w_l, i, 64);
    acc = fmaf(w, bf2f(V[r*64 + l]), acc);    // coalesced 128B row
  }
  agg[node*64 + l] = f2bf(acc);
}

// ============ Kernel 3: out = [H|agg] @ [Wself|Wout]^T + b + H ============
#define K3S 200
__global__ __launch_bounds__(256) void k3_out(
    const float* __restrict__ H, const ushort_t* __restrict__ agg,
    const float* __restrict__ Wself, const float* __restrict__ Wout,
    const float* __restrict__ Wob, const float* __restrict__ loss,
    float* __restrict__ out)
{
  __shared__ unsigned short Wl[128*K3S];
  __shared__ unsigned short Hs[64*K3S];
  const int tid = threadIdx.x;
  for (int idx = tid; idx < 128*24; idx += 256) {
    int c = idx / 24, k = (idx % 24) * 8;
    const float* src = (k < 128) ? (Wself + c*128 + k) : (Wout + c*64 + (k-128));
    *(u16x8*)&Wl[c*K3S + k] = pack2(*(const float4*)src, *(const float4*)(src+4));
  }
  __syncthreads();
  const int wv = tid >> 6, l = tid & 63, l15 = l & 15, lh = l >> 4;
  const float wob0 = Wob[wv*32 + l15], wob1 = Wob[wv*32 + 16 + l15];
  const int ntiles = (NN + 63) >> 6;
  for (int t = blockIdx.x; t < ntiles; t += gridDim.x) {
    const int nb = t * 64;
    {
      const int r = tid >> 2, q = tid & 3, row = nb + r;
      if (row < NN) {
        const float* hsrc = H + row*128 + q*32;
        #pragma unroll
        for (int s = 0; s < 4; ++s)
          *(u16x8*)&Hs[r*K3S + q*32 + s*8] =
              pack2(*(const float4*)(hsrc + s*8), *(const float4*)(hsrc + s*8 + 4));
        const ushort_t* asrc = agg + row*64 + q*16;   // agg already bf16
        *(u16x8*)&Hs[r*K3S + 128 + q*16]     = *(const u16x8*)asrc;
        *(u16x8*)&Hs[r*K3S + 128 + q*16 + 8] = *(const u16x8*)(asrc + 8);
      } else {
        #pragma unroll
        for (int s = 0; s < 4; ++s) *(u16x8*)&Hs[r*K3S + q*32 + s*8] = zero8();
        #pragma unroll
        for (int s = 0; s < 2; ++s) *(u16x8*)&Hs[r*K3S + 128 + q*16 + s*8] = zero8();
      }
    }
    __syncthreads();
    f32x4 acc[4][2];
    #pragma unroll
    for (int m = 0; m < 4; ++m) { acc[m][0] = zero4(); acc[m][1] = zero4(); }
    #pragma unroll
    for (int kk = 0; kk < 192; kk += 32) {
      const int kb = kk + lh*8;
      bf16x8 bf0 = *(const bf16x8*)&Wl[(wv*32 + l15)*K3S + kb];
      bf16x8 bf1 = *(const bf16x8*)&Wl[(wv*32 + 16 + l15)*K3S + kb];
      #pragma unroll
      for (int m = 0; m < 4; ++m) {
        bf16x8 af = *(const bf16x8*)&Hs[(m*16 + l15)*K3S + kb];
        acc[m][0] = MFMA(af, bf0, acc[m][0]);
        acc[m][1] = MFMA(af, bf1, acc[m][1]);
      }
    }
    #pragma unroll
    for (int m = 0; m < 4; ++m) {
      const int rowl = m*16 + lh*4;
      #pragma unroll
      for (int n = 0; n < 2; ++n) {
        const int col = wv*32 + n*16 + l15;
        const float wob = n ? wob1 : wob0;
        #pragma unroll
        for (int r = 0; r < 4; ++r) {
          const int node = nb + rowl + r;
          if (node < NN)
            out[node*128 + col] = acc[m][n][r] + wob + H[node*128 + col];
        }
      }
    }
    __syncthreads();
  }
  if (blockIdx.x == 0 && tid == 0) out[NN*128] = loss[0] * (1.0f / NE);
}

extern "C" void kernel_launch(void* const* d_in, const int* in_sizes, int n_in,
                              void* d_out, int out_size, void* d_ws, size_t ws_size,
                              hipStream_t stream) {
  const float* H     = (const float*)d_in[0];
  const float* Wv    = (const float*)d_in[1];
  const float* Wt    = (const float*)d_in[2];
  const float* semb  = (const float*)d_in[3];
  const float* w1    = (const float*)d_in[4];
  const float* b1    = (const float*)d_in[5];
  const float* w2    = (const float*)d_in[6];
  const float* b2    = (const float*)d_in[7];
  const float* Wself = (const float*)d_in[8];
  const float* Wout  = (const float*)d_in[9];
  const float* Wob   = (const float*)d_in[10];
  const int*   eidx  = (const int*)d_in[11];
  const int*   esign = (const int*)d_in[12];
  float* out = (float*)d_out;

  // d_ws layout: cursor[100K int] | loss f32 | pad | w_e[1.6M f32] | agg[6.4M bf16]
  int*      cursor = (int*)d_ws;                          // 400000 B
  float*    loss   = (float*)((char*)d_ws + 400000);      // 4 B
  float*    w_e    = (float*)((char*)d_ws + 400016);      // 6.4 MB, 16B-aligned
  ushort_t* agg    = (ushort_t*)((char*)d_ws + 6800016);  // 12.8 MB, 16B-aligned
  // d_out layout (scratch until k3 overwrites): V bf16 | T bf16 | elist int
  ushort_t* V = (ushort_t*)out;                 // 12.8 MB
  ushort_t* T = V + 6400000;                    // 12.8 MB
  int* elist = (int*)(out + 6400000);           // 25.6 MB (100K x 64 int)

  (void)hipMemsetAsync(d_ws, 0, 400016, stream);          // cursor + loss
  k1_vt    <<<768, 256, 0, stream>>>(H, Wv, Wt, V, T);
  k_fill   <<<2048, 256, 0, stream>>>(eidx, esign, cursor, elist);
  k2_alpha <<<512, 512, 0, stream>>>(V, T, semb, w1, b1, w2, b2, eidx, esign, w_e, loss);
  k2b_gather<<<25000, 256, 0, stream>>>(cursor, elist, w_e, eidx, V, agg);
  k3_out   <<<512, 256, 0, stream>>>(H, agg, Wself, Wout, Wob, loss, out);
}

// Round 10
// 278.819 us; speedup vs baseline: 2.6237x; 2.6237x over previous
//
#include <hip/hip_runtime.h>

#define NN 100000
#define NE 1600000
#define LAM 0.05f

typedef __attribute__((ext_vector_type(8))) short bf16x8;
typedef __attribute__((ext_vector_type(8))) unsigned short u16x8;
typedef __attribute__((ext_vector_type(4))) float f32x4;
typedef unsigned short ushort_t;

__device__ inline unsigned short f2bf(float x) {
  unsigned u = __builtin_bit_cast(unsigned, x);
  u = (u + 0x7FFFu + ((u >> 16) & 1u)) >> 16;
  return (unsigned short)u;
}
__device__ inline float bf2f(unsigned short h) {
  unsigned u = ((unsigned)h) << 16;
  return __builtin_bit_cast(float, u);
}
__device__ inline u16x8 pack2(float4 a, float4 b) {
  u16x8 p;
  p[0]=f2bf(a.x); p[1]=f2bf(a.y); p[2]=f2bf(a.z); p[3]=f2bf(a.w);
  p[4]=f2bf(b.x); p[5]=f2bf(b.y); p[6]=f2bf(b.z); p[7]=f2bf(b.w);
  return p;
}
__device__ inline u16x8 zero8() {
  u16x8 z;
  #pragma unroll
  for (int i = 0; i < 8; ++i) z[i] = 0;
  return z;
}
__device__ inline f32x4 zero4() {
  f32x4 z;
  z[0] = z[1] = z[2] = z[3] = 0.f;
  return z;
}
__device__ inline void atomic_pk_add_bf16(void* addr, unsigned pk) {
  asm volatile("global_atomic_pk_add_bf16 %0, %1, off"
               :: "v"(addr), "v"(pk) : "memory");
}

#define MFMA(a,b,c) __builtin_amdgcn_mfma_f32_16x16x32_bf16((bf16x8)(a),(bf16x8)(b),(c),0,0,0)

// ============ Kernel 1: V|T = H @ [Wv|Wt]^T via MFMA, bf16 output ============
#define K1S 136
__global__ __launch_bounds__(256) void k1_vt(
    const float* __restrict__ H, const float* __restrict__ Wv,
    const float* __restrict__ Wt, ushort_t* __restrict__ V, ushort_t* __restrict__ T)
{
  __shared__ unsigned short Wl[128*K1S];
  __shared__ unsigned short Hs[64*K1S];
  const int tid = threadIdx.x;
  for (int idx = tid; idx < 128*16; idx += 256) {
    int c = idx >> 4, k = (idx & 15) * 8;
    const float* src = (c < 64) ? (Wv + c*128 + k) : (Wt + (c-64)*128 + k);
    *(u16x8*)&Wl[c*K1S + k] = pack2(*(const float4*)src, *(const float4*)(src+4));
  }
  __syncthreads();
  const int wv = tid >> 6, l = tid & 63, l15 = l & 15, lh = l >> 4;
  const int ntiles = (NN + 63) >> 6;
  for (int t = blockIdx.x; t < ntiles; t += gridDim.x) {
    const int nb = t * 64;
    {
      const int r = tid >> 2, q = tid & 3, row = nb + r;
      if (row < NN) {
        const float* src = H + row*128 + q*32;
        #pragma unroll
        for (int s = 0; s < 4; ++s)
          *(u16x8*)&Hs[r*K1S + q*32 + s*8] =
              pack2(*(const float4*)(src + s*8), *(const float4*)(src + s*8 + 4));
      } else {
        #pragma unroll
        for (int s = 0; s < 4; ++s) *(u16x8*)&Hs[r*K1S + q*32 + s*8] = zero8();
      }
    }
    __syncthreads();
    f32x4 acc[4][2];
    #pragma unroll
    for (int m = 0; m < 4; ++m) { acc[m][0] = zero4(); acc[m][1] = zero4(); }
    #pragma unroll
    for (int kk = 0; kk < 128; kk += 32) {
      const int kb = kk + lh*8;
      bf16x8 bf0 = *(const bf16x8*)&Wl[(wv*32 + l15)*K1S + kb];
      bf16x8 bf1 = *(const bf16x8*)&Wl[(wv*32 + 16 + l15)*K1S + kb];
      #pragma unroll
      for (int m = 0; m < 4; ++m) {
        bf16x8 af = *(const bf16x8*)&Hs[(m*16 + l15)*K1S + kb];
        acc[m][0] = MFMA(af, bf0, acc[m][0]);
        acc[m][1] = MFMA(af, bf1, acc[m][1]);
      }
    }
    #pragma unroll
    for (int m = 0; m < 4; ++m) {
      const int rowl = m*16 + lh*4;
      #pragma unroll
      for (int n = 0; n < 2; ++n) {
        const int col = wv*32 + n*16 + l15;
        #pragma unroll
        for (int r = 0; r < 4; ++r) {
          const int node = nb + rowl + r;
          if (node < NN) {
            if (col < 64) V[node*64 + col] = f2bf(acc[m][n][r]);
            else          T[node*64 + col - 64] = f2bf(acc[m][n][r]);
          }
        }
      }
    }
    __syncthreads();
  }
}

// ============ Kernel 2: direct-gather edge MLP + pk-bf16 scatter, high-occ ============
// R8 state (best measured: 229us, atomic-rate-bound). 512 threads, LDS = w1 only.
#define WS 168
__global__ __launch_bounds__(512, 4) void k2_edge(
    const ushort_t* __restrict__ V, const ushort_t* __restrict__ T,
    const float* __restrict__ semb, const float* __restrict__ w1,
    const float* __restrict__ b1, const float* __restrict__ w2,
    const float* __restrict__ b2, const int* __restrict__ eidx,
    const int* __restrict__ esign, ushort_t* __restrict__ agg,
    float* __restrict__ loss)
{
  __shared__ unsigned short Wl[128*WS];      // w1 bf16 [hid][k], k 136..159 zero
  const int tid = threadIdx.x;
  for (int idx = tid; idx < 128*17; idx += 512) {
    int c = idx / 17, kc = (idx % 17) * 8;
    const float* src = w1 + c*136 + kc;
    *(u16x8*)&Wl[c*WS + kc] = pack2(*(const float4*)src, *(const float4*)(src+4));
  }
  for (int idx = tid; idx < 128*3; idx += 512) {
    int c = idx / 3, s = idx % 3;
    *(u16x8*)&Wl[c*WS + 136 + s*8] = zero8();
  }
  __syncthreads();

  const int wv = tid >> 6, l = tid & 63, l15 = l & 15, lh = l >> 4;
  const int h = l >> 5, lp = l & 31;        // scatter role: half h, lane-in-half
  float b1v[8], w2v[8];
  #pragma unroll
  for (int n = 0; n < 8; ++n) { b1v[n] = b1[n*16 + l15]; w2v[n] = w2[n*16 + l15]; }
  const float b2v = b2[0];
  float loss_acc = 0.f;

  const int wg = blockIdx.x*8 + wv, nw = gridDim.x*8;
  const int NT = NE / 16;

  int t = wg;
  int rj = 0, ci = 0, sg = 0;
  if (t < NT) {                              // per-lane: edge e = t*16 + l15
    const int e = t*16 + l15;
    rj = eidx[e]; ci = eidx[NE + e]; sg = esign[e];
  }
  for (; t < NT; t += nw) {
    // ---- A-fragments straight from global bf16 V/T ----
    bf16x8 A0 = *(const bf16x8*)&T[ci*64 + lh*8];
    bf16x8 A1 = *(const bf16x8*)&T[ci*64 + 32 + lh*8];
    bf16x8 A2 = *(const bf16x8*)&V[rj*64 + lh*8];
    bf16x8 A3 = *(const bf16x8*)&V[rj*64 + 32 + lh*8];
    bf16x8 A4;
    if (lh == 0) {
      const float* sp = semb + (sg + 1) * 8;
      A4 = (bf16x8)pack2(*(const float4*)sp, *(const float4*)(sp+4));
    } else A4 = (bf16x8)zero8();
    // ---- prefetch next tile's indices ----
    int rjn = 0, cin = 0, sgp = 0;
    const int tn = t + nw;
    if (tn < NT) {
      const int en = tn*16 + l15;
      rjn = eidx[en]; cin = eidx[NE + en]; sgp = esign[en];
    }
    // ---- MFMA: rows = 16 edges, cols = 128 hid, K = 160 ----
    f32x4 acc[8];
    #pragma unroll
    for (int n = 0; n < 8; ++n) acc[n] = zero4();
    __builtin_amdgcn_s_setprio(1);
    #pragma unroll
    for (int n = 0; n < 8; ++n) {
      const int rowb = (n*16 + l15)*WS;
      acc[n] = MFMA(A0, *(const bf16x8*)&Wl[rowb + lh*8],       acc[n]);
      acc[n] = MFMA(A1, *(const bf16x8*)&Wl[rowb + 32 + lh*8],  acc[n]);
      acc[n] = MFMA(A2, *(const bf16x8*)&Wl[rowb + 64 + lh*8],  acc[n]);
      acc[n] = MFMA(A3, *(const bf16x8*)&Wl[rowb + 96 + lh*8],  acc[n]);
      acc[n] = MFMA(A4, *(const bf16x8*)&Wl[rowb + 128 + lh*8], acc[n]);
    }
    __builtin_amdgcn_s_setprio(0);
    // ---- relu + w2 dot (in-lane over n), reduce over l15 ----
    f32x4 s;
    #pragma unroll
    for (int r = 0; r < 4; ++r) {
      float a = 0.f;
      #pragma unroll
      for (int n = 0; n < 8; ++n) {
        float hh = acc[n][r] + b1v[n];
        hh = fmaxf(hh, 0.f);
        a = fmaf(hh, w2v[n], a);
      }
      s[r] = a;
    }
    #pragma unroll
    for (int off = 1; off < 16; off <<= 1) {
      #pragma unroll
      for (int r = 0; r < 4; ++r) s[r] += __shfl_xor(s[r], off, 16);
    }
    f32x4 sa;                                   // alpha for edge lh*4+r
    #pragma unroll
    for (int r = 0; r < 4; ++r) {
      float a = s[r] + b2v;
      sa[r] = (a > LAM) ? (a - LAM) : ((a < -LAM) ? (a + LAM) : 0.f);
    }
    if (l15 == 0) {
      #pragma unroll
      for (int r = 0; r < 4; ++r) loss_acc += fabsf(sa[r]);
    }
    // ---- scatter: 2 edges/iter, 32 lanes/edge, packed bf16x2 atomics ----
    #pragma unroll
    for (int i = 0; i < 16; i += 2) {
      const float sa0b = __shfl(sa[i & 3],       ((i)     >> 2) * 16, 64);
      const float sa1b = __shfl(sa[(i + 1) & 3], ((i + 1) >> 2) * 16, 64);
      const int ci0 = __shfl(ci, i, 64),     ci1 = __shfl(ci, i + 1, 64);
      const int sg0 = __shfl(sg, i, 64),     sg1 = __shfl(sg, i + 1, 64);
      const int rj0 = __shfl(rj, i, 64),     rj1 = __shfl(rj, i + 1, 64);
      const float sab = h ? sa1b : sa0b;
      const int   cie = h ? ci1  : ci0;
      const int   sge = h ? sg1  : sg0;
      const int   rje = h ? rj1  : rj0;
      const float we = (sge > 0) ? sab : ((sge < 0) ? -fabsf(sab) : 0.f);
      if (we != 0.f) {
        const unsigned vv = *(const unsigned*)&V[rje*64 + lp*2];   // L2-warm
        const float vj0 = bf2f((unsigned short)(vv & 0xffffu));
        const float vj1 = bf2f((unsigned short)(vv >> 16));
        const unsigned pk = (unsigned)f2bf(we*vj0) | ((unsigned)f2bf(we*vj1) << 16);
        atomic_pk_add_bf16(&agg[cie*64 + lp*2], pk);
      }
    }
    rj = rjn; ci = cin; sg = sgp;
  }
  #pragma unroll
  for (int off = 1; off < 64; off <<= 1) loss_acc += __shfl_xor(loss_acc, off, 64);
  if (l == 0) atomicAdd(loss, loss_acc);
}

// ============ Kernel 3: out = [H|agg] @ [Wself|Wout]^T + b + H ============
#define K3S 200
__global__ __launch_bounds__(256) void k3_out(
    const float* __restrict__ H, const ushort_t* __restrict__ agg,
    const float* __restrict__ Wself, const float* __restrict__ Wout,
    const float* __restrict__ Wob, const float* __restrict__ loss,
    float* __restrict__ out)
{
  __shared__ unsigned short Wl[128*K3S];
  __shared__ unsigned short Hs[64*K3S];
  const int tid = threadIdx.x;
  for (int idx = tid; idx < 128*24; idx += 256) {
    int c = idx / 24, k = (idx % 24) * 8;
    const float* src = (k < 128) ? (Wself + c*128 + k) : (Wout + c*64 + (k-128));
    *(u16x8*)&Wl[c*K3S + k] = pack2(*(const float4*)src, *(const float4*)(src+4));
  }
  __syncthreads();
  const int wv = tid >> 6, l = tid & 63, l15 = l & 15, lh = l >> 4;
  const float wob0 = Wob[wv*32 + l15], wob1 = Wob[wv*32 + 16 + l15];
  const int ntiles = (NN + 63) >> 6;
  for (int t = blockIdx.x; t < ntiles; t += gridDim.x) {
    const int nb = t * 64;
    {
      const int r = tid >> 2, q = tid & 3, row = nb + r;
      if (row < NN) {
        const float* hsrc = H + row*128 + q*32;
        #pragma unroll
        for (int s = 0; s < 4; ++s)
          *(u16x8*)&Hs[r*K3S + q*32 + s*8] =
              pack2(*(const float4*)(hsrc + s*8), *(const float4*)(hsrc + s*8 + 4));
        const ushort_t* asrc = agg + row*64 + q*16;   // agg already bf16
        *(u16x8*)&Hs[r*K3S + 128 + q*16]     = *(const u16x8*)asrc;
        *(u16x8*)&Hs[r*K3S + 128 + q*16 + 8] = *(const u16x8*)(asrc + 8);
      } else {
        #pragma unroll
        for (int s = 0; s < 4; ++s) *(u16x8*)&Hs[r*K3S + q*32 + s*8] = zero8();
        #pragma unroll
        for (int s = 0; s < 2; ++s) *(u16x8*)&Hs[r*K3S + 128 + q*16 + s*8] = zero8();
      }
    }
    __syncthreads();
    f32x4 acc[4][2];
    #pragma unroll
    for (int m = 0; m < 4; ++m) { acc[m][0] = zero4(); acc[m][1] = zero4(); }
    #pragma unroll
    for (int kk = 0; kk < 192; kk += 32) {
      const int kb = kk + lh*8;
      bf16x8 bf0 = *(const bf16x8*)&Wl[(wv*32 + l15)*K3S + kb];
      bf16x8 bf1 = *(const bf16x8*)&Wl[(wv*32 + 16 + l15)*K3S + kb];
      #pragma unroll
      for (int m = 0; m < 4; ++m) {
        bf16x8 af = *(const bf16x8*)&Hs[(m*16 + l15)*K3S + kb];
        acc[m][0] = MFMA(af, bf0, acc[m][0]);
        acc[m][1] = MFMA(af, bf1, acc[m][1]);
      }
    }
    #pragma unroll
    for (int m = 0; m < 4; ++m) {
      const int rowl = m*16 + lh*4;
      #pragma unroll
      for (int n = 0; n < 2; ++n) {
        const int col = wv*32 + n*16 + l15;
        const float wob = n ? wob1 : wob0;
        #pragma unroll
        for (int r = 0; r < 4; ++r) {
          const int node = nb + rowl + r;
          if (node < NN)
            out[node*128 + col] = acc[m][n][r] + wob + H[node*128 + col];
        }
      }
    }
    __syncthreads();
  }
  if (blockIdx.x == 0 && tid == 0) out[NN*128] = loss[0] * (1.0f / NE);
}

extern "C" void kernel_launch(void* const* d_in, const int* in_sizes, int n_in,
                              void* d_out, int out_size, void* d_ws, size_t ws_size,
                              hipStream_t stream) {
  const float* H     = (const float*)d_in[0];
  const float* Wv    = (const float*)d_in[1];
  const float* Wt    = (const float*)d_in[2];
  const float* semb  = (const float*)d_in[3];
  const float* w1    = (const float*)d_in[4];
  const float* b1    = (const float*)d_in[5];
  const float* w2    = (const float*)d_in[6];
  const float* b2    = (const float*)d_in[7];
  const float* Wself = (const float*)d_in[8];
  const float* Wout  = (const float*)d_in[9];
  const float* Wob   = (const float*)d_in[10];
  const int*   eidx  = (const int*)d_in[11];
  const int*   esign = (const int*)d_in[12];
  float* out = (float*)d_out;

  ushort_t* agg  = (ushort_t*)d_ws;                 // 100000*64 bf16 (12.8MB)
  float* loss = (float*)((char*)d_ws + 12800000);   // 1 f32
  ushort_t* V = (ushort_t*)out;                     // bf16 scratch in d_out
  ushort_t* T = V + 6400000;                        // k3 overwrites out fully

  (void)hipMemsetAsync(d_ws, 0, 12800004, stream);
  k1_vt  <<<768, 256, 0, stream>>>(H, Wv, Wt, V, T);
  k2_edge<<<512, 512, 0, stream>>>(V, T, semb, w1, b1, w2, b2, eidx, esign, agg, loss);
  k3_out <<<512, 256, 0, stream>>>(H, agg, Wself, Wout, Wob, loss, out);
}